// Round 11
// baseline (284.260 us; speedup 1.0000x reference)
//
#include <hip/hip_runtime.h>

#define D 128
#define BN_EPS 1e-5f
#define CHUNK 4096   // edges per block in bucket passes (256 thr x 16)

typedef __attribute__((ext_vector_type(8))) short bf16x8;
typedef __attribute__((ext_vector_type(4))) float f32x4;

// RNE round f32 -> bf16 (returns low 16)
__device__ __forceinline__ unsigned short bf16r(float a) {
    unsigned u = __float_as_uint(a);
    u += 0x7fff + ((u >> 16) & 1);
    return (unsigned short)(u >> 16);
}
__device__ __forceinline__ unsigned bf16pairp(float a, float b) {
    return (unsigned)bf16r(a) | ((unsigned)bf16r(b) << 16);
}

// ---------------- F1: bucket hist + row-degree count + W prep ----------------
// Blocks [0,nchunks): bucket hist (dst>>8) + global row count atomics.
// Blocks [nchunks, nchunks+128): WT[c][k] = bf16(W[k][c]) for W1,W2.
__global__ __launch_bounds__(256) void k_f1(const int* __restrict__ dst,
                                            int* __restrict__ bcnt,
                                            int* __restrict__ cnt,
                                            int E, int nb, int nchunks,
                                            const float* __restrict__ W1,
                                            const float* __restrict__ W2,
                                            unsigned short* __restrict__ WT1,
                                            unsigned short* __restrict__ WT2) {
    int tid = threadIdx.x;
    if (blockIdx.x >= nchunks) {
        int t = (blockIdx.x - nchunks) * 256 + tid;   // 0..32767
        const float* W = (t < 16384) ? W1 : W2;
        unsigned short* WT = (t < 16384) ? WT1 : WT2;
        int i = t & 16383;
        int k = i >> 7, c = i & 127;
        WT[c * 128 + k] = bf16r(W[k * 128 + c]);
        return;
    }
    __shared__ int h[256];
    h[tid] = 0;
    __syncthreads();
    int base = blockIdx.x * CHUNK + tid;
#pragma unroll
    for (int k = 0; k < 16; k++) {
        int i = base + k * 256;
        if (i < E) {
            int t = dst[i];
            atomicAdd(&h[t >> 8], 1);
            atomicAdd(&cnt[t], 1);
        }
    }
    __syncthreads();
    if (tid < nb && h[tid]) atomicAdd(&bcnt[tid], h[tid]);
}

// ---------------- F2: bucket scan (block 0, + zero sums) + dinv (blocks 1..) --------
__global__ __launch_bounds__(256) void k_f2(const int* __restrict__ bcnt,
                                            int* __restrict__ bbase,
                                            int* __restrict__ bcur,
                                            float* __restrict__ sums,
                                            const int* __restrict__ cnt,
                                            float* __restrict__ dinv,
                                            int nb, int E, int n) {
    int tid = threadIdx.x;
    if (blockIdx.x > 0) {
        int i = (blockIdx.x - 1) * 256 + tid;
        if (i < n) dinv[i] = rsqrtf((float)(cnt[i] + 1));   // +1 = self loop
        return;
    }
    __shared__ int sh[256];
    sums[tid] = 0.f;   // 256 floats: colsum + colsumsq for BN
    int v = (tid < nb) ? bcnt[tid] : 0;
    sh[tid] = v;
    __syncthreads();
    for (int off = 1; off < 256; off <<= 1) {
        int u = (tid >= off) ? sh[tid - off] : 0;
        __syncthreads();
        sh[tid] += u;
        __syncthreads();
    }
    if (tid < nb) {
        bbase[tid] = sh[tid] - v;
        bcur[tid] = sh[tid] - v;
    }
    if (tid == 0) bbase[nb] = E;
}

// ---------------- MFMA GEMM body: Yb = bf16(dinv .* (f(X) @ W)) ----------------
// 64 rows/block, 256 thr (4 waves). mfma_f32_16x16x32_bf16, verified layouts.
#define AST 136   // bf16 row stride (pad 128+8)
__device__ __forceinline__ void gemm_body(int bid, int tid,
                                          const float* __restrict__ X,
                                          const unsigned short* __restrict__ WT,
                                          const float* __restrict__ sc,
                                          const float* __restrict__ dinv,
                                          unsigned short* __restrict__ Yb, int n,
                                          unsigned short* Abf, unsigned short* Bbf) {
    int row0 = bid * 64;
#pragma unroll
    for (int p = 0; p < 8; p++) {
        int idx = tid + p * 256;
        int c = idx >> 4, s = idx & 15;
        uint4 v = ((const uint4*)(WT + c * 128))[s];
        *(uint4*)&Bbf[c * AST + s * 8] = v;
    }
#pragma unroll
    for (int p = 0; p < 8; p++) {
        int idx = tid + p * 256;
        int r = idx >> 5, k4 = idx & 31;
        int grow = row0 + r;
        float4 v = make_float4(0.f, 0.f, 0.f, 0.f);
        if (grow < n)
            v = *(const float4*)(X + (size_t)grow * D + k4 * 4);
        if (sc) {
            float4 scl = ((const float4*)sc)[k4];
            float4 sh  = ((const float4*)(sc + D))[k4];
            v.x = fmaxf(fmaf(v.x, scl.x, sh.x), 0.f);
            v.y = fmaxf(fmaf(v.y, scl.y, sh.y), 0.f);
            v.z = fmaxf(fmaf(v.z, scl.z, sh.z), 0.f);
            v.w = fmaxf(fmaf(v.w, scl.w, sh.w), 0.f);
        }
        uint2 pk;
        pk.x = bf16pairp(v.x, v.y);
        pk.y = bf16pairp(v.z, v.w);
        *(uint2*)&Abf[r * AST + k4 * 4] = pk;
    }
    __syncthreads();

    int w = tid >> 6, lane = tid & 63;
    int m = lane & 15, quad = lane >> 4;

    bf16x8 av[4];
#pragma unroll
    for (int ks = 0; ks < 4; ks++)
        av[ks] = *(const bf16x8*)&Abf[(w * 16 + m) * AST + ks * 32 + quad * 8];

    f32x4 acc[8];
#pragma unroll
    for (int ct = 0; ct < 8; ct++) acc[ct] = (f32x4){0.f, 0.f, 0.f, 0.f};

#pragma unroll
    for (int ct = 0; ct < 8; ct++) {
#pragma unroll
        for (int ks = 0; ks < 4; ks++) {
            bf16x8 bv = *(const bf16x8*)&Bbf[(ct * 16 + m) * AST + ks * 32 + quad * 8];
            acc[ct] = __builtin_amdgcn_mfma_f32_16x16x32_bf16(av[ks], bv, acc[ct], 0, 0, 0);
        }
    }

    float dv[4];
    int rb = row0 + w * 16 + quad * 4;
#pragma unroll
    for (int r = 0; r < 4; r++) dv[r] = (rb + r < n) ? dinv[rb + r] : 0.f;
#pragma unroll
    for (int ct = 0; ct < 8; ct++) {
#pragma unroll
        for (int r = 0; r < 4; r++) {
            int grow = rb + r;
            if (grow < n)
                Yb[(size_t)grow * D + ct * 16 + m] = bf16r(acc[ct][r] * dv[r]);
        }
    }
}

// ---------------- F3: bucket scatter (packed u32) + GEMM1 fused ----------------
// Blocks [0,nchunks): scatter (dst&255)<<16 | src into bucket runs.
// Blocks [nchunks, nchunks+ngemm): conv1 GEMM (dinv/WT ready after F2/F1).
__global__ __launch_bounds__(256) void k_f3(const int* __restrict__ src,
                                            const int* __restrict__ dst,
                                            int* __restrict__ bcur,
                                            unsigned* __restrict__ bpack,
                                            int E, int nb, int nchunks,
                                            const float* __restrict__ X,
                                            const unsigned short* __restrict__ WT,
                                            const float* __restrict__ dinv,
                                            unsigned short* __restrict__ Yb, int n) {
    __shared__ unsigned short Abf[64 * AST];
    __shared__ unsigned short Bbf[128 * AST];
    int tid = threadIdx.x;
    if (blockIdx.x >= nchunks) {
        gemm_body(blockIdx.x - nchunks, tid, X, WT, nullptr, dinv, Yb, n, Abf, Bbf);
        return;
    }
    int* h = (int*)Abf;   // reuse LDS
    h[tid] = 0;
    __syncthreads();
    int base = blockIdx.x * CHUNK + tid;
    int s[16], t[16], r[16];
#pragma unroll
    for (int k = 0; k < 16; k++) {
        int i = base + k * 256;
        if (i < E) {
            s[k] = src[i];
            t[k] = dst[i];
            r[k] = atomicAdd(&h[t[k] >> 8], 1);
        } else {
            t[k] = -1;
        }
    }
    __syncthreads();
    if (tid < nb) {
        int c = h[tid];
        h[tid] = c ? atomicAdd(&bcur[tid], c) : 0;
    }
    __syncthreads();
#pragma unroll
    for (int k = 0; k < 16; k++) {
        if (t[k] >= 0)
            bpack[h[t[k] >> 8] + r[k]] = ((unsigned)(t[k] & 255) << 16) | (unsigned)s[k];
    }
}

// ---------------- F4: per-bucket CSR finalize (rowptr + ushort csr) ----------------
// Row counts from cnt (global); LDS scan only; scatter bpack -> csr window.
__global__ __launch_bounds__(256) void k_f4(const unsigned* __restrict__ bpack,
                                            const int* __restrict__ bbase,
                                            const int* __restrict__ cnt,
                                            int* __restrict__ rowptr,
                                            unsigned short* __restrict__ csr,
                                            int n, int nb, int E) {
    int b = blockIdx.x;
    int tid = threadIdx.x;
    int lo = bbase[b], hi = bbase[b + 1];
    __shared__ int sh[256];
    __shared__ int h[256];
    int row = b * 256 + tid;
    int c = (row < n) ? cnt[row] : 0;
    sh[tid] = c;
    __syncthreads();
    for (int off = 1; off < 256; off <<= 1) {
        int u = (tid >= off) ? sh[tid - off] : 0;
        __syncthreads();
        sh[tid] += u;
        __syncthreads();
    }
    int ex = sh[tid] - c;
    if (row < n) rowptr[row] = lo + ex;
    if (b == 0 && tid == 0) rowptr[n] = E;
    h[tid] = lo + ex;
    __syncthreads();
    for (int i = lo + tid; i < hi; i += 256) {
        unsigned p = bpack[i];
        int pos = atomicAdd(&h[p >> 16], 1);
        csr[pos] = (unsigned short)(p & 0xffffu);
    }
}

// ---------------- slot-gather aggregation: one wave per row, 4 edges/instr ----------
__device__ __forceinline__ void unpack_add(uint4 u, float* acc) {
    acc[0] += __uint_as_float(u.x << 16);
    acc[1] += __uint_as_float(u.x & 0xffff0000u);
    acc[2] += __uint_as_float(u.y << 16);
    acc[3] += __uint_as_float(u.y & 0xffff0000u);
    acc[4] += __uint_as_float(u.z << 16);
    acc[5] += __uint_as_float(u.z & 0xffff0000u);
    acc[6] += __uint_as_float(u.w << 16);
    acc[7] += __uint_as_float(u.w & 0xffff0000u);
}

__global__ __launch_bounds__(256) void k_agg(const unsigned short* __restrict__ Hb,
                                             const unsigned short* __restrict__ csr_src,
                                             const int* __restrict__ rowptr,
                                             const float* __restrict__ dinv,
                                             const float* __restrict__ bias,
                                             float* __restrict__ OUT, int n) {
    int row = blockIdx.x * 4 + (threadIdx.x >> 6);
    if (row >= n) return;
    int lane = threadIdx.x & 63;
    int slot = lane >> 4, seg = lane & 15;
    const uint4* HB4 = (const uint4*)Hb;

    float acc[8];
#pragma unroll
    for (int i = 0; i < 8; i++) acc[i] = 0.f;
    if (slot == 0) {                       // self term once
        uint4 us = HB4[(size_t)row * 16 + seg];
        unpack_add(us, acc);
    }

    int k0 = rowptr[row], k1 = rowptr[row + 1];
    int deg = k1 - k0;
    int iters = deg >> 2;
    int k = k0 + slot;
    int it = 0;
    for (; it + 4 <= iters; it += 4, k += 16) {
        int s0 = csr_src[k], s1 = csr_src[k + 4];
        int s2 = csr_src[k + 8], s3 = csr_src[k + 12];
        uint4 u0 = HB4[(size_t)s0 * 16 + seg];
        uint4 u1 = HB4[(size_t)s1 * 16 + seg];
        uint4 u2 = HB4[(size_t)s2 * 16 + seg];
        uint4 u3 = HB4[(size_t)s3 * 16 + seg];
        unpack_add(u0, acc);
        unpack_add(u1, acc);
        unpack_add(u2, acc);
        unpack_add(u3, acc);
    }
    for (; it < iters; it++, k += 4) {
        int s = csr_src[k];
        uint4 u = HB4[(size_t)s * 16 + seg];
        unpack_add(u, acc);
    }
    if (slot < (deg & 3)) {                // tail edges
        int s = csr_src[k];
        uint4 u = HB4[(size_t)s * 16 + seg];
        unpack_add(u, acc);
    }

#pragma unroll
    for (int i = 0; i < 8; i++) {
        acc[i] += __shfl_xor(acc[i], 16, 64);
        acc[i] += __shfl_xor(acc[i], 32, 64);
    }

    float dt = dinv[row];
    float v0 = acc[slot * 2] * dt;
    float v1 = acc[slot * 2 + 1] * dt;
    int cp = seg * 4 + slot;               // float2 index = col/2
    if (bias) {
        float2 b = ((const float2*)bias)[cp];
        v0 += b.x;
        v1 += b.y;
    }
    ((float2*)OUT)[(size_t)row * 64 + cp] = make_float2(v0, v1);
}

// ---------------- standalone GEMM (conv2) ----------------
__global__ __launch_bounds__(256) void k_gemm(const float* __restrict__ X,
                                              const unsigned short* __restrict__ WT,
                                              const float* __restrict__ sc,
                                              const float* __restrict__ dinv,
                                              unsigned short* __restrict__ Yb, int n) {
    __shared__ unsigned short Abf[64 * AST];
    __shared__ unsigned short Bbf[128 * AST];
    gemm_body(blockIdx.x, threadIdx.x, X, WT, sc, dinv, Yb, n, Abf, Bbf);
}

// ---------------- BN stats / finalize ----------------
__global__ __launch_bounds__(128) void k_bn_stats(const float* __restrict__ A,
                                                  float* __restrict__ sums, int n) {
    int j = threadIdx.x;
    float s = 0.f, ss = 0.f;
    for (int r = blockIdx.x; r < n; r += gridDim.x) {
        float v = A[(size_t)r * D + j];
        s += v;
        ss += v * v;
    }
    atomicAdd(&sums[j], s);
    atomicAdd(&sums[D + j], ss);
}

// sc[0:128]=scale, sc[128:256]=shift.  (b1 cancels exactly in BN — omitted.)
__global__ __launch_bounds__(128) void k_bn_finalize(const float* __restrict__ sums,
                                                     const float* __restrict__ gamma,
                                                     const float* __restrict__ beta,
                                                     float* __restrict__ sc, int n) {
    int j = threadIdx.x;
    float inv_n = 1.0f / (float)n;
    float mu = sums[j] * inv_n;
    float var = sums[D + j] * inv_n - mu * mu;
    float is = rsqrtf(var + BN_EPS);
    float scale = gamma[j] * is;
    sc[j] = scale;
    sc[D + j] = beta[j] - mu * scale;
}

extern "C" void kernel_launch(void* const* d_in, const int* in_sizes, int n_in,
                              void* d_out, int out_size, void* d_ws, size_t ws_size,
                              hipStream_t stream) {
    const float* x     = (const float*)d_in[0];
    const int*   ei    = (const int*)d_in[1];
    const float* W1    = (const float*)d_in[2];
    // d_in[3] = b1 — cancels exactly in BatchNorm, unused
    const float* gamma = (const float*)d_in[4];
    const float* beta  = (const float*)d_in[5];
    const float* W2    = (const float*)d_in[6];
    const float* b2    = (const float*)d_in[7];
    float* out = (float*)d_out;

    int n = in_sizes[0] / D;   // 50000 (< 65536 — ushort indices valid)
    int E = in_sizes[1] / 2;   // 800000
    const int* src = ei;
    const int* dst = ei + E;
    int nb = (n + 255) >> 8;          // 196 buckets (must be <= 256)
    int nchunks = (E + CHUNK - 1) / CHUNK;
    int ngemm = (n + 63) / 64;

    char* ws = (char*)d_ws;
    size_t off = 0;
    auto alloc = [&](size_t bytes) {
        char* p = ws + off;
        off = (off + bytes + 511) & ~(size_t)511;
        return p;
    };
    size_t szH = (size_t)n * D * sizeof(float);
    float*          agg    = (float*)alloc(szH);                  // conv1 agg / BN input
    unsigned short* hbf    = (unsigned short*)alloc((size_t)n * D * 2);  // bf16 payload
    float*          dinv   = (float*)alloc(n * sizeof(float));
    int*            rowptr = (int*)alloc((n + 1) * sizeof(int));
    int*            cnt    = (int*)alloc((size_t)(n + 256) * sizeof(int));
    int*            bcnt   = cnt + n;                             // adjacent: one memset
    int*            bbase  = (int*)alloc(257 * sizeof(int));
    int*            bcur   = (int*)alloc(256 * sizeof(int));
    unsigned*       bpack  = (unsigned*)alloc((size_t)E * sizeof(unsigned));
    unsigned short* csr    = (unsigned short*)alloc((size_t)E * sizeof(unsigned short));
    unsigned short* wt1    = (unsigned short*)alloc(16384 * 2);
    unsigned short* wt2    = (unsigned short*)alloc(16384 * 2);
    float*          sums   = (float*)alloc(2 * D * sizeof(float));
    float*          sc     = (float*)alloc(2 * D * sizeof(float));

    hipMemsetAsync(cnt, 0, (size_t)(n + 256) * sizeof(int), stream);

    // F1: bucket hist + row counts + W prep
    k_f1<<<nchunks + 128, 256, 0, stream>>>(dst, bcnt, cnt, E, nb, nchunks,
                                            W1, W2, wt1, wt2);
    // F2: bucket scan (+zero sums) + dinv
    k_f2<<<1 + (n + 255) / 256, 256, 0, stream>>>(bcnt, bbase, bcur, sums,
                                                  cnt, dinv, nb, E, n);
    // F3: packed bucket scatter + conv1 GEMM (overlapped)
    k_f3<<<nchunks + ngemm, 256, 0, stream>>>(src, dst, bcur, bpack, E, nb, nchunks,
                                              x, wt1, dinv, hbf, n);
    // F4: CSR finalize (rowptr + ushort csr)
    k_f4<<<nb, 256, 0, stream>>>(bpack, bbase, cnt, rowptr, csr, n, nb, E);

    // conv1 aggregate
    k_agg<<<(n + 3) / 4, 256, 0, stream>>>(hbf, csr, rowptr, dinv, nullptr, agg, n);

    // BN stats -> scale/shift (ReLU fused into GEMM2 load)
    k_bn_stats<<<512, 128, 0, stream>>>(agg, sums, n);
    k_bn_finalize<<<1, 128, 0, stream>>>(sums, gamma, beta, sc, n);

    // conv2: GEMM + aggregate (+b2)
    k_gemm<<<ngemm, 256, 0, stream>>>(agg, wt2, sc, dinv, hbf, n);
    k_agg<<<(n + 3) / 4, 256, 0, stream>>>(hbf, csr, rowptr, dinv, b2, out, n);
}

// Round 12
// 282.944 us; speedup vs baseline: 1.0047x; 1.0047x over previous
//
#include <hip/hip_runtime.h>

#define D 128
#define BN_EPS 1e-5f
#define CHUNK 4096   // edges per block in bucket passes (256 thr x 16)

typedef __attribute__((ext_vector_type(8))) short bf16x8;
typedef __attribute__((ext_vector_type(4))) float f32x4;

// RNE round f32 -> bf16 (returns low 16)
__device__ __forceinline__ unsigned short bf16r(float a) {
    unsigned u = __float_as_uint(a);
    u += 0x7fff + ((u >> 16) & 1);
    return (unsigned short)(u >> 16);
}
__device__ __forceinline__ unsigned bf16pairp(float a, float b) {
    return (unsigned)bf16r(a) | ((unsigned)bf16r(b) << 16);
}

// ---------------- P1: bucket histogram + W prep + fused bucket scan ----------------
// Blocks [0,nchunks): hist (dst>>8). Blocks [nchunks,nchunks+128): WT[c][k]=bf16(W[k][c]).
// Last hist block (device counter) performs the bucket scan -> bbase/bcur, zeros sums.
__global__ __launch_bounds__(256) void k_bhist(const int* __restrict__ dst,
                                               int* __restrict__ bcnt, int E, int nb,
                                               int nchunks,
                                               const float* __restrict__ W1,
                                               const float* __restrict__ W2,
                                               unsigned short* __restrict__ WT1,
                                               unsigned short* __restrict__ WT2,
                                               int* __restrict__ done,
                                               int* __restrict__ bbase,
                                               int* __restrict__ bcur,
                                               float* __restrict__ sums) {
    int tid = threadIdx.x;
    if (blockIdx.x >= nchunks) {
        int t = (blockIdx.x - nchunks) * 256 + tid;   // 0..32767
        const float* W = (t < 16384) ? W1 : W2;
        unsigned short* WT = (t < 16384) ? WT1 : WT2;
        int i = t & 16383;
        int k = i >> 7, c = i & 127;
        WT[c * 128 + k] = bf16r(W[k * 128 + c]);
        return;
    }
    __shared__ int h[256];
    __shared__ int lastflag;
    h[tid] = 0;
    __syncthreads();
    int base = blockIdx.x * CHUNK + tid;
#pragma unroll
    for (int k = 0; k < 16; k++) {
        int i = base + k * 256;
        if (i < E) atomicAdd(&h[dst[i] >> 8], 1);
    }
    __syncthreads();
    if (tid < nb && h[tid]) atomicAdd(&bcnt[tid], h[tid]);
    __threadfence();
    __syncthreads();
    if (tid == 0) lastflag = (atomicAdd(done, 1) == nchunks - 1) ? 1 : 0;
    __syncthreads();
    if (!lastflag) return;
    // ---- last block: scan bucket counts (device-coherent reads via RMW) ----
    sums[tid] = 0.f;   // 256 floats: colsum + colsumsq for BN
    int v = (tid < nb) ? atomicAdd(&bcnt[tid], 0) : 0;
    h[tid] = v;
    __syncthreads();
    for (int off = 1; off < 256; off <<= 1) {
        int u = (tid >= off) ? h[tid - off] : 0;
        __syncthreads();
        h[tid] += u;
        __syncthreads();
    }
    if (tid < nb) {
        bbase[tid] = h[tid] - v;
        bcur[tid] = h[tid] - v;
    }
    if (tid == 0) bbase[nb] = E;
}

// ---------------- P3: bucket scatter of (src,dst) pairs, run-coalesced ----------------
__global__ __launch_bounds__(256) void k_bscatter(const int* __restrict__ src,
                                                  const int* __restrict__ dst,
                                                  int* __restrict__ bcur,
                                                  int2* __restrict__ bpairs,
                                                  int E, int nb) {
    __shared__ int h[256];
    int tid = threadIdx.x;
    h[tid] = 0;
    __syncthreads();
    int base = blockIdx.x * CHUNK + tid;
    int s[16], t[16], r[16];
#pragma unroll
    for (int k = 0; k < 16; k++) {
        int i = base + k * 256;
        if (i < E) {
            s[k] = src[i];
            t[k] = dst[i];
            r[k] = atomicAdd(&h[t[k] >> 8], 1);
        } else {
            t[k] = -1;
        }
    }
    __syncthreads();
    if (tid < nb) {
        int c = h[tid];
        h[tid] = c ? atomicAdd(&bcur[tid], c) : 0;
    }
    __syncthreads();
#pragma unroll
    for (int k = 0; k < 16; k++) {
        if (t[k] >= 0) bpairs[h[t[k] >> 8] + r[k]] = make_int2(s[k], t[k]);
    }
}

// ---------------- P4: per-bucket CSR finalize (rowptr, dinv, ushort csr) ------------
__global__ __launch_bounds__(256) void k_csr(const int2* __restrict__ bpairs,
                                             const int* __restrict__ bbase,
                                             int* __restrict__ rowptr,
                                             unsigned short* __restrict__ csr,
                                             float* __restrict__ dinv,
                                             int n, int nb, int E) {
    int b = blockIdx.x;
    int tid = threadIdx.x;
    int lo = bbase[b], hi = bbase[b + 1];
    __shared__ int h[256];
    __shared__ int sh[256];
    h[tid] = 0;
    __syncthreads();
    for (int i = lo + tid; i < hi; i += 256) atomicAdd(&h[bpairs[i].y & 255], 1);
    __syncthreads();
    int c = h[tid];
    sh[tid] = c;
    __syncthreads();
    for (int off = 1; off < 256; off <<= 1) {
        int u = (tid >= off) ? sh[tid - off] : 0;
        __syncthreads();
        sh[tid] += u;
        __syncthreads();
    }
    int ex = sh[tid] - c;
    int row = b * 256 + tid;
    if (row < n) {
        rowptr[row] = lo + ex;
        dinv[row] = rsqrtf((float)(c + 1));   // +1 = self loop
    }
    if (b == 0 && tid == 0) rowptr[n] = E;
    __syncthreads();
    h[tid] = lo + ex;   // reuse as cursor
    __syncthreads();
    for (int i = lo + tid; i < hi; i += 256) {
        int2 p = bpairs[i];
        int pos = atomicAdd(&h[p.y & 255], 1);
        csr[pos] = (unsigned short)p.x;
    }
}

// ---------------- slot-gather aggregation: one wave per row, 4 edges/instr ----------
// Lane L: slot = L>>4, seg = L&15. Hb row = 16 uint4 segs; one instr = 4 edges' rows.
// OUT[t] = ( Hb[t] + sum_{s in N(t)} Hb[s] ) * dinv[t] + bias   (payload pre-scaled)
__device__ __forceinline__ void unpack_add(uint4 u, float* acc) {
    acc[0] += __uint_as_float(u.x << 16);
    acc[1] += __uint_as_float(u.x & 0xffff0000u);
    acc[2] += __uint_as_float(u.y << 16);
    acc[3] += __uint_as_float(u.y & 0xffff0000u);
    acc[4] += __uint_as_float(u.z << 16);
    acc[5] += __uint_as_float(u.z & 0xffff0000u);
    acc[6] += __uint_as_float(u.w << 16);
    acc[7] += __uint_as_float(u.w & 0xffff0000u);
}

__global__ __launch_bounds__(256) void k_agg(const unsigned short* __restrict__ Hb,
                                             const unsigned short* __restrict__ csr_src,
                                             const int* __restrict__ rowptr,
                                             const float* __restrict__ dinv,
                                             const float* __restrict__ bias,
                                             float* __restrict__ OUT, int n) {
    int row = blockIdx.x * 4 + (threadIdx.x >> 6);
    if (row >= n) return;
    int lane = threadIdx.x & 63;
    int slot = lane >> 4, seg = lane & 15;
    const uint4* HB4 = (const uint4*)Hb;

    float acc[8];
#pragma unroll
    for (int i = 0; i < 8; i++) acc[i] = 0.f;
    if (slot == 0) {                       // self term once
        uint4 us = HB4[(size_t)row * 16 + seg];
        unpack_add(us, acc);
    }

    int k0 = rowptr[row], k1 = rowptr[row + 1];
    int deg = k1 - k0;
    int iters = deg >> 2;
    int k = k0 + slot;
    int it = 0;
    for (; it + 4 <= iters; it += 4, k += 16) {
        int s0 = csr_src[k], s1 = csr_src[k + 4];
        int s2 = csr_src[k + 8], s3 = csr_src[k + 12];
        uint4 u0 = HB4[(size_t)s0 * 16 + seg];
        uint4 u1 = HB4[(size_t)s1 * 16 + seg];
        uint4 u2 = HB4[(size_t)s2 * 16 + seg];
        uint4 u3 = HB4[(size_t)s3 * 16 + seg];
        unpack_add(u0, acc);
        unpack_add(u1, acc);
        unpack_add(u2, acc);
        unpack_add(u3, acc);
    }
    for (; it < iters; it++, k += 4) {
        int s = csr_src[k];
        uint4 u = HB4[(size_t)s * 16 + seg];
        unpack_add(u, acc);
    }
    if (slot < (deg & 3)) {                // tail edges
        int s = csr_src[k];
        uint4 u = HB4[(size_t)s * 16 + seg];
        unpack_add(u, acc);
    }

#pragma unroll
    for (int i = 0; i < 8; i++) {
        acc[i] += __shfl_xor(acc[i], 16, 64);
        acc[i] += __shfl_xor(acc[i], 32, 64);
    }

    float dt = dinv[row];
    float v0 = acc[slot * 2] * dt;
    float v1 = acc[slot * 2 + 1] * dt;
    int cp = seg * 4 + slot;               // float2 index = col/2
    if (bias) {
        float2 b = ((const float2*)bias)[cp];
        v0 += b.x;
        v1 += b.y;
    }
    ((float2*)OUT)[(size_t)row * 64 + cp] = make_float2(v0, v1);
}

// ---------------- MFMA GEMM: Yb = bf16(dinv .* (f(X) @ W)) ----------------
// 64 rows/block, 256 thr (4 waves). mfma_f32_16x16x32_bf16, verified layouts.
// f = identity if sc==null, else relu(x*scale+shift), sc[0:128]=scale,[128:256]=shift
#define AST 136   // bf16 row stride (pad 128+8)
__global__ __launch_bounds__(256) void k_gemm(const float* __restrict__ X,
                                              const unsigned short* __restrict__ WT,
                                              const float* __restrict__ sc,
                                              const float* __restrict__ dinv,
                                              unsigned short* __restrict__ Yb, int n) {
    __shared__ unsigned short Abf[64 * AST];
    __shared__ unsigned short Bbf[128 * AST];
    int tid = threadIdx.x;
    int row0 = blockIdx.x * 64;

#pragma unroll
    for (int p = 0; p < 8; p++) {
        int idx = tid + p * 256;
        int c = idx >> 4, s = idx & 15;
        uint4 v = ((const uint4*)(WT + c * 128))[s];
        *(uint4*)&Bbf[c * AST + s * 8] = v;
    }
#pragma unroll
    for (int p = 0; p < 8; p++) {
        int idx = tid + p * 256;
        int r = idx >> 5, k4 = idx & 31;
        int grow = row0 + r;
        float4 v = make_float4(0.f, 0.f, 0.f, 0.f);
        if (grow < n)
            v = *(const float4*)(X + (size_t)grow * D + k4 * 4);
        if (sc) {
            float4 scl = ((const float4*)sc)[k4];
            float4 sh  = ((const float4*)(sc + D))[k4];
            v.x = fmaxf(fmaf(v.x, scl.x, sh.x), 0.f);
            v.y = fmaxf(fmaf(v.y, scl.y, sh.y), 0.f);
            v.z = fmaxf(fmaf(v.z, scl.z, sh.z), 0.f);
            v.w = fmaxf(fmaf(v.w, scl.w, sh.w), 0.f);
        }
        uint2 pk;
        pk.x = bf16pairp(v.x, v.y);
        pk.y = bf16pairp(v.z, v.w);
        *(uint2*)&Abf[r * AST + k4 * 4] = pk;
    }
    __syncthreads();

    int w = tid >> 6, lane = tid & 63;
    int m = lane & 15, quad = lane >> 4;

    bf16x8 av[4];
#pragma unroll
    for (int ks = 0; ks < 4; ks++)
        av[ks] = *(const bf16x8*)&Abf[(w * 16 + m) * AST + ks * 32 + quad * 8];

    f32x4 acc[8];
#pragma unroll
    for (int ct = 0; ct < 8; ct++) acc[ct] = (f32x4){0.f, 0.f, 0.f, 0.f};

#pragma unroll
    for (int ct = 0; ct < 8; ct++) {
#pragma unroll
        for (int ks = 0; ks < 4; ks++) {
            bf16x8 bv = *(const bf16x8*)&Bbf[(ct * 16 + m) * AST + ks * 32 + quad * 8];
            acc[ct] = __builtin_amdgcn_mfma_f32_16x16x32_bf16(av[ks], bv, acc[ct], 0, 0, 0);
        }
    }

    float dv[4];
    int rb = row0 + w * 16 + quad * 4;
#pragma unroll
    for (int r = 0; r < 4; r++) dv[r] = (rb + r < n) ? dinv[rb + r] : 0.f;
#pragma unroll
    for (int ct = 0; ct < 8; ct++) {
#pragma unroll
        for (int r = 0; r < 4; r++) {
            int grow = rb + r;
            if (grow < n)
                Yb[(size_t)grow * D + ct * 16 + m] = bf16r(acc[ct][r] * dv[r]);
        }
    }
}

// ---------------- BN stats + fused finalize (last block) ----------------
// sums[0:128]=colsum, sums[128:256]=colsumsq; last block computes sc (scale/shift).
// (b1 cancels exactly in BN — omitted.)
__global__ __launch_bounds__(128) void k_bn_stats(const float* __restrict__ A,
                                                  float* __restrict__ sums,
                                                  int* __restrict__ done,
                                                  const float* __restrict__ gamma,
                                                  const float* __restrict__ beta,
                                                  float* __restrict__ sc, int n) {
    int j = threadIdx.x;
    float s = 0.f, ss = 0.f;
    for (int r = blockIdx.x; r < n; r += gridDim.x) {
        float v = A[(size_t)r * D + j];
        s += v;
        ss += v * v;
    }
    atomicAdd(&sums[j], s);
    atomicAdd(&sums[D + j], ss);
    __threadfence();
    __syncthreads();
    __shared__ int lastflag;
    if (j == 0) lastflag = (atomicAdd(done, 1) == (int)gridDim.x - 1) ? 1 : 0;
    __syncthreads();
    if (!lastflag) return;
    float ts = atomicAdd(&sums[j], 0.f);        // device-coherent read
    float tss = atomicAdd(&sums[D + j], 0.f);
    float inv_n = 1.0f / (float)n;
    float mu = ts * inv_n;
    float var = tss * inv_n - mu * mu;
    float is = rsqrtf(var + BN_EPS);
    float scale = gamma[j] * is;
    sc[j] = scale;
    sc[D + j] = beta[j] - mu * scale;
}

extern "C" void kernel_launch(void* const* d_in, const int* in_sizes, int n_in,
                              void* d_out, int out_size, void* d_ws, size_t ws_size,
                              hipStream_t stream) {
    const float* x     = (const float*)d_in[0];
    const int*   ei    = (const int*)d_in[1];
    const float* W1    = (const float*)d_in[2];
    // d_in[3] = b1 — cancels exactly in BatchNorm, unused
    const float* gamma = (const float*)d_in[4];
    const float* beta  = (const float*)d_in[5];
    const float* W2    = (const float*)d_in[6];
    const float* b2    = (const float*)d_in[7];
    float* out = (float*)d_out;

    int n = in_sizes[0] / D;   // 50000 (< 65536 — ushort indices valid)
    int E = in_sizes[1] / 2;   // 800000
    const int* src = ei;
    const int* dst = ei + E;
    int nb = (n + 255) >> 8;          // 196 buckets (must be <= 256)
    int nchunks = (E + CHUNK - 1) / CHUNK;
    int ngemm = (n + 63) / 64;

    char* ws = (char*)d_ws;
    size_t off = 0;
    auto alloc = [&](size_t bytes) {
        char* p = ws + off;
        off = (off + bytes + 511) & ~(size_t)511;
        return p;
    };
    size_t szH = (size_t)n * D * sizeof(float);
    float*          agg    = (float*)alloc(szH);                  // conv1 agg / BN input
    unsigned short* hbf    = (unsigned short*)alloc((size_t)n * D * 2);  // bf16 payload
    float*          dinv   = (float*)alloc(n * sizeof(float));
    int*            rowptr = (int*)alloc((n + 1) * sizeof(int));
    int*            bcnt   = (int*)alloc(258 * sizeof(int));      // +2 done counters
    int*            done1  = bcnt + 256;
    int*            done2  = bcnt + 257;
    int*            bbase  = (int*)alloc(257 * sizeof(int));
    int*            bcur   = (int*)alloc(256 * sizeof(int));
    int2*           bpairs = (int2*)alloc((size_t)E * sizeof(int2));
    unsigned short* csr    = (unsigned short*)alloc((size_t)E * sizeof(unsigned short));
    unsigned short* wt1    = (unsigned short*)alloc(16384 * 2);
    unsigned short* wt2    = (unsigned short*)alloc(16384 * 2);
    float*          sums   = (float*)alloc(2 * D * sizeof(float));
    float*          sc     = (float*)alloc(2 * D * sizeof(float));

    hipMemsetAsync(bcnt, 0, 258 * sizeof(int), stream);

    // CSR build: hist (+W prep, + fused bucket scan) -> pair scatter -> finalize
    k_bhist<<<nchunks + 128, 256, 0, stream>>>(dst, bcnt, E, nb, nchunks,
                                               W1, W2, wt1, wt2,
                                               done1, bbase, bcur, sums);
    k_bscatter<<<nchunks, 256, 0, stream>>>(src, dst, bcur, bpairs, E, nb);
    k_csr<<<nb, 256, 0, stream>>>(bpairs, bbase, rowptr, csr, dinv, n, nb, E);

    // conv1: hbf = bf16(dinv .* (x@W1)); agg = aggregate(hbf)
    k_gemm<<<ngemm, 256, 0, stream>>>(x, wt1, nullptr, dinv, hbf, n);
    k_agg<<<(n + 3) / 4, 256, 0, stream>>>(hbf, csr, rowptr, dinv, nullptr, agg, n);

    // BN stats + fused finalize (ReLU folded into GEMM2 load)
    k_bn_stats<<<512, 128, 0, stream>>>(agg, sums, done2, gamma, beta, sc, n);

    // conv2: GEMM + aggregate (+b2)
    k_gemm<<<ngemm, 256, 0, stream>>>(agg, wt2, sc, dinv, hbf, n);
    k_agg<<<(n + 3) / 4, 256, 0, stream>>>(hbf, csr, rowptr, dinv, b2, out, n);
}